// Round 1
// baseline (152.085 us; speedup 1.0000x reference)
//
#include <hip/hip_runtime.h>
#include <hip/hip_bf16.h>
#include <math.h>

// Problem constants: B=8, S=1024, D=768, H=12, DH=64. fp32 in, fp32 out.
constexpr int Bn = 8, Sn = 1024, Dn = 768, Hn = 12, DHn = 64;
// sqrt(log2(e)/sqrt(DH)) — folded into Wq,bq,Wk,bk so scores come out
// pre-scaled for exp2. 0.42466086^2 = 0.18033688 = 0.125*log2(e).
constexpr float SQC = 0.42466086f;

typedef __attribute__((ext_vector_type(8))) short bf16x8;  // 8 bf16 = 4 VGPRs
typedef __attribute__((ext_vector_type(4))) float f32x4;   // MFMA 16x16 C/D

// pack 2 floats -> 2 bf16 (round-nearest) in 3 VALU ops: add, add, perm
__device__ __forceinline__ unsigned int pk2bf(float a, float b) {
    union { float f; unsigned u; } ca{a}, cb{b};
    return __builtin_amdgcn_perm(cb.u + 0x8000u, ca.u + 0x8000u, 0x07060302u);
}

// Build a W^T A/B-fragment (rows e, k = d) straight from fp32 W[h][d][e]:
// element j of chunk kc = W[d = kc*32 + quad*8 + j][e] * sc.
__device__ __forceinline__ bf16x8 wfrag(const float* __restrict__ W,
                                        int e, int kc, int quad, float sc) {
    const float* p = W + (size_t)(kc * 32 + quad * 8) * 64 + e;
    unsigned int tmp[4];
    #pragma unroll
    for (int j = 0; j < 4; j++)
        tmp[j] = pk2bf(p[(2 * j) * 64] * sc, p[(2 * j + 1) * 64] * sc);
    return *(bf16x8*)tmp;
}

// ---------------------------------------------------------------------------
// Single fused kernel: Q-proj prologue + per-k-tile K/V projection + flash
// attention. The old proj_kernel and its 50MB k_ws/vt_ws HBM roundtrip are
// gone; each q-tile block recomputes its K/V tiles from x (L2-resident per
// XCD since b == xcd under the swizzle).
//
// Software pipeline (2 barriers/iter, same as before):
//   iter kt, pre-B : commit Ks/Vt(kt) from regs; stage Xs(kt+1) from rx regs
//   iter kt, post-B: prefetch x(kt+2)->rx; K/V-proj(kt+1)->regs;
//                    QK^T/softmax/PV on tile kt
// ---------------------------------------------------------------------------
__global__ __launch_bounds__(256, 3) void mhsa_fused_kernel(
    const float* __restrict__ x,
    const float* __restrict__ Wq, const float* __restrict__ bq,
    const float* __restrict__ Wk, const float* __restrict__ bk,
    const float* __restrict__ Wv, const float* __restrict__ bv,
    float* __restrict__ out)
{
    __shared__ unsigned short Xs[64 * 72];       // [s][d] bf16 x-tile
    __shared__ unsigned short Ks[64 * 72];       // [key][e]
    __shared__ unsigned short Vt[64 * 72];       // [e][key]
    __shared__ unsigned short Pws[4 * 32 * 72];  // per-wave P / Q staging

    const int blk = blockIdx.x;    // 768 = 8 XCD * 12 bh * 8 qt
    const int xcd = blk & 7;
    const int idx = blk >> 3;      // 0..95
    const int bh  = xcd * 12 + (idx % 12);   // b == xcd -> x[b] fits XCD L2
    const int qt  = idx / 12;      // 0..7 (128-query tiles)
    const int t    = threadIdx.x;
    const int w    = t >> 6;
    const int lane = t & 63;
    const int l    = lane & 15;
    const int quad = lane >> 4;
    const int sr   = t >> 2;            // staging row
    const int sc0  = (t & 3) * 16;      // staging col base

    const int b = bh / Hn, h = bh % Hn;
    unsigned short* Pw = Pws + w * 32 * 72;
    const float* xh = x + (size_t)b * Sn * Dn + h * 64;  // [s][64], stride Dn

    // ---- hoisted K/V weight fragments + biases (L2-hot strided reads) ----
    const int e = w * 16 + l;
    bf16x8 wkf[2], wvf[2];
    #pragma unroll
    for (int kc = 0; kc < 2; kc++) {
        wkf[kc] = wfrag(Wk + (size_t)h * 4096, e, kc, quad, SQC);
        wvf[kc] = wfrag(Wv + (size_t)h * 4096, e, kc, quad, 1.0f);
    }
    float4 bkv = *(const float4*)(bk + h * 64 + w * 16 + quad * 4);
    bkv.x *= SQC; bkv.y *= SQC; bkv.z *= SQC; bkv.w *= SQC;
    const float bvl = bv[h * 64 + e];

    // ---- x-tile(0) register prefetch ----
    float4 rx[4];
    #pragma unroll
    for (int q4 = 0; q4 < 4; q4++)
        rx[q4] = ((const float4*)(xh + (size_t)sr * Dn + sc0))[q4];

    // ---- Q-projection prologue: 32 queries per wave (unchanged) ----
    bf16x8 qf[2][2];
    {
        bf16x8 xq[2][2];
        #pragma unroll
        for (int st = 0; st < 2; st++) {
            const float* xp = x + ((size_t)(b * Sn + qt * 128 + w * 32 + st * 16 + l) * Dn
                                   + h * 64 + quad * 8);
            #pragma unroll
            for (int kc = 0; kc < 2; kc++) {
                float4 v0 = *(const float4*)(xp + kc * 32);
                float4 v1 = *(const float4*)(xp + kc * 32 + 4);
                unsigned int tmp[4] = {pk2bf(v0.x, v0.y), pk2bf(v0.z, v0.w),
                                       pk2bf(v1.x, v1.y), pk2bf(v1.z, v1.w)};
                xq[st][kc] = *(bf16x8*)tmp;
            }
        }
        #pragma unroll
        for (int nt = 0; nt < 4; nt++) {
            bf16x8 wa0 = wfrag(Wq + (size_t)h * 4096, nt * 16 + l, 0, quad, SQC);
            bf16x8 wa1 = wfrag(Wq + (size_t)h * 4096, nt * 16 + l, 1, quad, SQC);
            float4 bqv = *(const float4*)(bq + h * 64 + nt * 16 + quad * 4);
            #pragma unroll
            for (int st = 0; st < 2; st++) {
                f32x4 acc = (f32x4){bqv.x * SQC, bqv.y * SQC, bqv.z * SQC, bqv.w * SQC};
                acc = __builtin_amdgcn_mfma_f32_16x16x32_bf16(wa0, xq[st][0], acc, 0, 0, 0);
                acc = __builtin_amdgcn_mfma_f32_16x16x32_bf16(wa1, xq[st][1], acc, 0, 0, 0);
                *(uint2*)&Pw[(st * 16 + l) * 72 + nt * 16 + quad * 4] =
                    make_uint2(pk2bf(acc[0], acc[1]), pk2bf(acc[2], acc[3]));
            }
        }
        __asm__ volatile("s_waitcnt lgkmcnt(0)" ::: "memory");
        #pragma unroll
        for (int st = 0; st < 2; st++) {
            qf[st][0] = *(bf16x8*)&Pw[(st * 16 + l) * 72 + quad * 8];
            qf[st][1] = *(bf16x8*)&Pw[(st * 16 + l) * 72 + 32 + quad * 8];
        }
    }

    // ---- stage Xs(0) ----
    {
        unsigned int tmp[8];
        #pragma unroll
        for (int q4 = 0; q4 < 4; q4++) {
            tmp[2 * q4]     = pk2bf(rx[q4].x, rx[q4].y);
            tmp[2 * q4 + 1] = pk2bf(rx[q4].z, rx[q4].w);
        }
        *(uint4*)&Xs[sr * 72 + sc0]     = ((uint4*)tmp)[0];
        *(uint4*)&Xs[sr * 72 + sc0 + 8] = ((uint4*)tmp)[1];
    }
    __syncthreads();   // Xs(0) ready

    // ---- K/V projection of tile 0 -> packed regs ----
    uint2 kpk[4], vpk[4];
    {
        bf16x8 xf[4][2];
        #pragma unroll
        for (int nt = 0; nt < 4; nt++)
            #pragma unroll
            for (int kc = 0; kc < 2; kc++)
                xf[nt][kc] = *(bf16x8*)&Xs[(nt * 16 + l) * 72 + kc * 32 + quad * 8];
        #pragma unroll
        for (int nt = 0; nt < 4; nt++) {
            f32x4 ak = (f32x4){bkv.x, bkv.y, bkv.z, bkv.w};
            ak = __builtin_amdgcn_mfma_f32_16x16x32_bf16(wkf[0], xf[nt][0], ak, 0, 0, 0);
            ak = __builtin_amdgcn_mfma_f32_16x16x32_bf16(wkf[1], xf[nt][1], ak, 0, 0, 0);
            kpk[nt] = make_uint2(pk2bf(ak[0], ak[1]), pk2bf(ak[2], ak[3]));
            f32x4 av = (f32x4){bvl, bvl, bvl, bvl};
            av = __builtin_amdgcn_mfma_f32_16x16x32_bf16(xf[nt][0], wvf[0], av, 0, 0, 0);
            av = __builtin_amdgcn_mfma_f32_16x16x32_bf16(xf[nt][1], wvf[1], av, 0, 0, 0);
            vpk[nt] = make_uint2(pk2bf(av[0], av[1]), pk2bf(av[2], av[3]));
        }
    }
    // ---- x-tile(1) prefetch ----
    #pragma unroll
    for (int q4 = 0; q4 < 4; q4++)
        rx[q4] = ((const float4*)(xh + (size_t)(64 + sr) * Dn + sc0))[q4];

    f32x4 Oa[2][4];
    #pragma unroll
    for (int st = 0; st < 2; st++)
        #pragma unroll
        for (int nt = 0; nt < 4; nt++) Oa[st][nt] = (f32x4){0.f, 0.f, 0.f, 0.f};
    float ps[2] = {0.f, 0.f};

    for (int kt = 0; kt < 16; kt++) {
        __syncthreads();   // A: prev readers of Ks/Vt/Xs done
        #pragma unroll
        for (int nt = 0; nt < 4; nt++) {   // commit K/V(kt) from regs
            *(uint2*)&Ks[(nt * 16 + l) * 72 + w * 16 + quad * 4] = kpk[nt];
            *(uint2*)&Vt[(w * 16 + l) * 72 + nt * 16 + quad * 4] = vpk[nt];
        }
        if (kt < 15) {   // stage Xs(kt+1) from rx regs
            unsigned int tmp[8];
            #pragma unroll
            for (int q4 = 0; q4 < 4; q4++) {
                tmp[2 * q4]     = pk2bf(rx[q4].x, rx[q4].y);
                tmp[2 * q4 + 1] = pk2bf(rx[q4].z, rx[q4].w);
            }
            *(uint4*)&Xs[sr * 72 + sc0]     = ((uint4*)tmp)[0];
            *(uint4*)&Xs[sr * 72 + sc0 + 8] = ((uint4*)tmp)[1];
        }
        __syncthreads();   // B: Ks/Vt(kt) + Xs(kt+1) visible

        if (kt < 14) {   // x-tile(kt+2) prefetch; completes during compute
            #pragma unroll
            for (int q4 = 0; q4 < 4; q4++)
                rx[q4] = ((const float4*)(xh + (size_t)((kt + 2) * 64 + sr) * Dn + sc0))[q4];
        }
        if (kt < 15) {   // K/V projection of tile kt+1 -> regs
            bf16x8 xf[4][2];
            #pragma unroll
            for (int nt = 0; nt < 4; nt++)
                #pragma unroll
                for (int kc = 0; kc < 2; kc++)
                    xf[nt][kc] = *(bf16x8*)&Xs[(nt * 16 + l) * 72 + kc * 32 + quad * 8];
            #pragma unroll
            for (int nt = 0; nt < 4; nt++) {
                f32x4 ak = (f32x4){bkv.x, bkv.y, bkv.z, bkv.w};
                ak = __builtin_amdgcn_mfma_f32_16x16x32_bf16(wkf[0], xf[nt][0], ak, 0, 0, 0);
                ak = __builtin_amdgcn_mfma_f32_16x16x32_bf16(wkf[1], xf[nt][1], ak, 0, 0, 0);
                kpk[nt] = make_uint2(pk2bf(ak[0], ak[1]), pk2bf(ak[2], ak[3]));
                f32x4 av = (f32x4){bvl, bvl, bvl, bvl};
                av = __builtin_amdgcn_mfma_f32_16x16x32_bf16(xf[nt][0], wvf[0], av, 0, 0, 0);
                av = __builtin_amdgcn_mfma_f32_16x16x32_bf16(xf[nt][1], wvf[1], av, 0, 0, 0);
                vpk[nt] = make_uint2(pk2bf(av[0], av[1]), pk2bf(av[2], av[3]));
            }
        }

        // ---- S^T per key-strip nt: A = K rows, B = Q; exp2 + packed P ----
        #pragma unroll
        for (int nt = 0; nt < 4; nt++) {
            bf16x8 kf0 = *(bf16x8*)&Ks[(nt * 16 + l) * 72 + quad * 8];
            bf16x8 kf1 = *(bf16x8*)&Ks[(nt * 16 + l) * 72 + 32 + quad * 8];
            #pragma unroll
            for (int st = 0; st < 2; st++) {
                f32x4 s = (f32x4){0.f, 0.f, 0.f, 0.f};
                s = __builtin_amdgcn_mfma_f32_16x16x32_bf16(kf0, qf[st][0], s, 0, 0, 0);
                s = __builtin_amdgcn_mfma_f32_16x16x32_bf16(kf1, qf[st][1], s, 0, 0, 0);
                float p0 = exp2f(s[0]), p1 = exp2f(s[1]);
                float p2 = exp2f(s[2]), p3 = exp2f(s[3]);
                ps[st] += (p0 + p1) + (p2 + p3);
                *(uint2*)&Pw[(st * 16 + l) * 72 + nt * 16 + quad * 4] =
                    make_uint2(pk2bf(p0, p1), pk2bf(p2, p3));
            }
        }
        __asm__ volatile("s_waitcnt lgkmcnt(0)" ::: "memory");

        bf16x8 pf[2][2];
        #pragma unroll
        for (int st = 0; st < 2; st++) {
            pf[st][0] = *(bf16x8*)&Pw[(st * 16 + l) * 72 + quad * 8];
            pf[st][1] = *(bf16x8*)&Pw[(st * 16 + l) * 72 + 32 + quad * 8];
        }

        // ---- O += P.V : B = V^T rows from LDS, shared across strips ----
        #pragma unroll
        for (int nt = 0; nt < 4; nt++) {
            bf16x8 vf0 = *(bf16x8*)&Vt[(nt * 16 + l) * 72 + quad * 8];
            bf16x8 vf1 = *(bf16x8*)&Vt[(nt * 16 + l) * 72 + 32 + quad * 8];
            #pragma unroll
            for (int st = 0; st < 2; st++) {
                Oa[st][nt] = __builtin_amdgcn_mfma_f32_16x16x32_bf16(pf[st][0], vf0, Oa[st][nt], 0, 0, 0);
                Oa[st][nt] = __builtin_amdgcn_mfma_f32_16x16x32_bf16(pf[st][1], vf1, Oa[st][nt], 0, 0, 0);
            }
        }
    }

    // fold partial sums across the 4 quads (keys), fetch per-query inv
    #pragma unroll
    for (int st = 0; st < 2; st++) {
        ps[st] += __shfl_xor(ps[st], 16, 64);
        ps[st] += __shfl_xor(ps[st], 32, 64);
    }
    #pragma unroll
    for (int st = 0; st < 2; st++) {
        float inv[4];
        #pragma unroll
        for (int r = 0; r < 4; r++) inv[r] = 1.0f / __shfl(ps[st], quad * 4 + r, 64);
        #pragma unroll
        for (int nt = 0; nt < 4; nt++)
            #pragma unroll
            for (int r = 0; r < 4; r++) {
                int srow = qt * 128 + w * 32 + st * 16 + quad * 4 + r;
                out[(size_t)(b * Sn + srow) * Dn + h * 64 + nt * 16 + l] = Oa[st][nt][r] * inv[r];
            }
    }
}

// ---------------------------------------------------------------------------
extern "C" void kernel_launch(void* const* d_in, const int* in_sizes, int n_in,
                              void* d_out, int out_size, void* d_ws, size_t ws_size,
                              hipStream_t stream) {
    const float* x  = (const float*)d_in[0];
    const float* Wq = (const float*)d_in[1];
    const float* bq = (const float*)d_in[2];
    const float* Wk = (const float*)d_in[3];
    const float* bk = (const float*)d_in[4];
    const float* Wv = (const float*)d_in[5];
    const float* bv = (const float*)d_in[6];

    hipLaunchKernelGGL(mhsa_fused_kernel, dim3(Bn * Hn * 8), dim3(256), 0, stream,
                       x, Wq, bq, Wk, bk, Wv, bv, (float*)d_out);
}